// Round 4
// baseline (8689.412 us; speedup 1.0000x reference)
//
#include <hip/hip_runtime.h>

#define TSEQ 2048
#define NB   32
#define HIDN 256
#define NG   1024   // 4*HID

typedef _Float16 half_t;
typedef _Float16 half2_t __attribute__((ext_vector_type(2)));

__device__ __forceinline__ float fdot2f16(unsigned int a, unsigned int b, float c) {
#if __has_builtin(__builtin_amdgcn_fdot2)
    return __builtin_amdgcn_fdot2(__builtin_bit_cast(half2_t, a),
                                  __builtin_bit_cast(half2_t, b), c, false);
#else
    half2_t x = __builtin_bit_cast(half2_t, a);
    half2_t y = __builtin_bit_cast(half2_t, b);
    return c + (float)x[0] * (float)y[0] + (float)x[1] * (float)y[1];
#endif
}

__device__ __forceinline__ unsigned int packh2(float lo, float hi) {
    half_t l = (half_t)lo, h = (half_t)hi;
    return (unsigned int)__builtin_bit_cast(unsigned short, l) |
           ((unsigned int)__builtin_bit_cast(unsigned short, h) << 16);
}

__device__ __forceinline__ float fast_exp2(float x) {
#if __has_builtin(__builtin_amdgcn_exp2f)
    return __builtin_amdgcn_exp2f(x);
#else
    return exp2f(x);
#endif
}
__device__ __forceinline__ float fast_rcp(float x) {
#if __has_builtin(__builtin_amdgcn_rcpf)
    return __builtin_amdgcn_rcpf(x);
#else
    return 1.0f / x;
#endif
}

__device__ __forceinline__ float sigf(float x) {
    // 1/(1+e^-x) = 1/(1+2^(-x*log2e))
    float e = fast_exp2(x * -1.442695041f);
    return fast_rcp(1.0f + e);
}
__device__ __forceinline__ float tanh_fast(float x) {
    // tanh = 1 - 2/(e^{2x}+1)
    float e = fast_exp2(x * 2.885390082f);
    return 1.0f - 2.0f * fast_rcp(e + 1.0f);
}

// ---------------------------------------------------------------------------
// K1: pack Wh and Wi (fp32 [256][1024]) into f16-pair uint4 layout:
//   Wp[m4][t], m4 in [0,32), t in [0,1024).
//   Column owned by t: col = (t&3)*256 + (t>>2)   (gate = t&3, j = t>>2)
//   Component d (d=0..3): pair (W[m4*8+2d][col], W[m4*8+2d+1][col])
// ---------------------------------------------------------------------------
__global__ void pack_w(const float* __restrict__ Wi, const float* __restrict__ Wh,
                       uint4* __restrict__ Whp, uint4* __restrict__ Wip) {
    int idx = blockIdx.x * 256 + threadIdx.x;   // 0..65535
    const float* W = (idx < 32768) ? Wh : Wi;
    uint4* dst     = (idx < 32768) ? Whp : Wip;
    int li  = idx & 32767;
    int m4  = li >> 10;
    int tt  = li & 1023;
    int col = (tt & 3) * 256 + (tt >> 2);
    unsigned int d0, d1, d2, d3;
    {
        int k0 = m4 * 8;
        d0 = packh2(W[(k0 + 0) * NG + col], W[(k0 + 1) * NG + col]);
        d1 = packh2(W[(k0 + 2) * NG + col], W[(k0 + 3) * NG + col]);
        d2 = packh2(W[(k0 + 4) * NG + col], W[(k0 + 5) * NG + col]);
        d3 = packh2(W[(k0 + 6) * NG + col], W[(k0 + 7) * NG + col]);
    }
    dst[li] = make_uint4(d0, d1, d2, d3);
}

// ---------------------------------------------------------------------------
// K2: x_proj GEMM: X [65536][256] fp32 @ Wi -> XP [65536][256] ushort4
//     (gate-interleaved f16: component g of XP[row*256+j] = x_proj[row][g*256+j])
// One WG: 1024 threads = (j in [0,256)) x (rq in [0,4)); 32 rows per WG.
// ---------------------------------------------------------------------------
__global__ __launch_bounds__(1024) void xproj_gemm(
    const float* __restrict__ X, const uint4* __restrict__ Wip,
    ushort4* __restrict__ XP)
{
    __shared__ uint4 atile[32][32];   // [row][k-chunk] 8 f16 each = 16KB
    const int tid = threadIdx.x;
    const long row0 = (long)blockIdx.x * 32;

    {   // stage + convert A tile
        int r = tid >> 5, kc = tid & 31;
        const float4* src = (const float4*)(X + (row0 + r) * 256 + kc * 8);
        float4 f0 = src[0], f1 = src[1];
        atile[r][kc] = make_uint4(packh2(f0.x, f0.y), packh2(f0.z, f0.w),
                                  packh2(f1.x, f1.y), packh2(f1.z, f1.w));
    }
    __syncthreads();

    const int j = tid & 255, rq = tid >> 8;
    float acc[8][4];
#pragma unroll
    for (int r = 0; r < 8; ++r)
#pragma unroll
        for (int g = 0; g < 4; ++g) acc[r][g] = 0.f;

    unsigned off = (unsigned)(j * 4);
#pragma unroll 2
    for (int m4 = 0; m4 < 32; ++m4) {
        uint4 w0 = Wip[off + 0];
        uint4 w1 = Wip[off + 1];
        uint4 w2 = Wip[off + 2];
        uint4 w3 = Wip[off + 3];
#pragma unroll
        for (int rr = 0; rr < 8; ++rr) {
            uint4 av = atile[rq * 8 + rr][m4];
            acc[rr][0] = fdot2f16(w0.x, av.x, acc[rr][0]);
            acc[rr][0] = fdot2f16(w0.y, av.y, acc[rr][0]);
            acc[rr][0] = fdot2f16(w0.z, av.z, acc[rr][0]);
            acc[rr][0] = fdot2f16(w0.w, av.w, acc[rr][0]);
            acc[rr][1] = fdot2f16(w1.x, av.x, acc[rr][1]);
            acc[rr][1] = fdot2f16(w1.y, av.y, acc[rr][1]);
            acc[rr][1] = fdot2f16(w1.z, av.z, acc[rr][1]);
            acc[rr][1] = fdot2f16(w1.w, av.w, acc[rr][1]);
            acc[rr][2] = fdot2f16(w2.x, av.x, acc[rr][2]);
            acc[rr][2] = fdot2f16(w2.y, av.y, acc[rr][2]);
            acc[rr][2] = fdot2f16(w2.z, av.z, acc[rr][2]);
            acc[rr][2] = fdot2f16(w2.w, av.w, acc[rr][2]);
            acc[rr][3] = fdot2f16(w3.x, av.x, acc[rr][3]);
            acc[rr][3] = fdot2f16(w3.y, av.y, acc[rr][3]);
            acc[rr][3] = fdot2f16(w3.z, av.z, acc[rr][3]);
            acc[rr][3] = fdot2f16(w3.w, av.w, acc[rr][3]);
        }
        off += 1024;
    }

#pragma unroll
    for (int rr = 0; rr < 8; ++rr) {
        long row = row0 + rq * 8 + rr;
        XP[row * 256 + j] = make_ushort4(
            __builtin_bit_cast(unsigned short, (half_t)acc[rr][0]),
            __builtin_bit_cast(unsigned short, (half_t)acc[rr][1]),
            __builtin_bit_cast(unsigned short, (half_t)acc[rr][2]),
            __builtin_bit_cast(unsigned short, (half_t)acc[rr][3]));
    }
}

// ---------------------------------------------------------------------------
// K3: persistent recurrence. One WG (1024 threads) per batch row, 32 WGs.
// Thread tid owns gate column col = (tid&3)*256 + (tid>>2).
// Per step:  phase A: z[col] = dot(h_f16, Wh[:,col]) + xp + b; a = act(z) -> aLDS
//            barrier; phase B (tid<256): combine 4 gates, update c, write h (f16,
//            double-buffered LDS) + ys; barrier.
// ---------------------------------------------------------------------------
__global__ __launch_bounds__(1024) void lstm_rec(
    const uint4* __restrict__ Whp, const unsigned short* __restrict__ XPh,
    const float* __restrict__ bias, const float* __restrict__ h0,
    const float* __restrict__ c0, float* __restrict__ out)
{
    __shared__ __align__(16) unsigned int hpair[2][128];  // 256 f16 per buf
    __shared__ __align__(16) float aLDS[NG];

    const int tid  = threadIdx.x;
    const int b    = blockIdx.x;
    const int gate = tid & 3;
    const int j    = tid >> 2;
    const int col  = gate * 256 + j;
    const float bc = bias[col];

    if (tid < 256) {
        ((unsigned short*)hpair[0])[tid] =
            __builtin_bit_cast(unsigned short, (half_t)h0[b * HIDN + tid]);
    }
    float c_state = (tid < 256) ? c0[b * HIDN + tid] : 0.f;

    const unsigned short* xp = XPh + (long)b * TSEQ * NG;  // halves
    float* ys = out + 2 * NB * HIDN + (long)b * TSEQ * HIDN;
    __syncthreads();

    int buf = 0;
    for (int step = 0; step < TSEQ; ++step) {
        // coalesced 2B load: quad lanes (gate 0..3) read 8B contiguous
        float xpf = (float)__builtin_bit_cast(half_t,
                        xp[(long)step * NG + j * 4 + gate]);

        float z0 = 0.f, z1 = 0.f, z2 = 0.f, z3 = 0.f;
        unsigned off = (unsigned)tid;
#pragma unroll
        for (int m4 = 0; m4 < 32; ++m4) {
            uint4 w  = Whp[off];                                   // coalesced L2 stream
            uint4 hv = *(const uint4*)&hpair[buf][m4 * 4];         // LDS broadcast
            z0 = fdot2f16(w.x, hv.x, z0);
            z1 = fdot2f16(w.y, hv.y, z1);
            z2 = fdot2f16(w.z, hv.z, z2);
            z3 = fdot2f16(w.w, hv.w, z3);
            off += 1024;
        }
        float z = (z0 + z1) + (z2 + z3) + xpf + bc;
        aLDS[tid] = (gate == 2) ? tanh_fast(z) : sigf(z);
        __syncthreads();

        if (tid < 256) {
            float4 a4 = *(const float4*)&aLDS[tid * 4];  // (i, f, g~, o)
            float cn = a4.y * c_state + a4.x * a4.z;
            float hn = a4.w * tanh_fast(cn);
            c_state = cn;
            ((unsigned short*)hpair[buf ^ 1])[tid] =
                __builtin_bit_cast(unsigned short, (half_t)hn);
            ys[(long)step * HIDN + tid] = hn;
            if (step == TSEQ - 1) {
                out[b * HIDN + tid] = hn;                 // hT
                out[NB * HIDN + b * HIDN + tid] = cn;     // cT
            }
        }
        __syncthreads();
        buf ^= 1;
    }
}

// ---------------------------------------------------------------------------
extern "C" void kernel_launch(void* const* d_in, const int* in_sizes, int n_in,
                              void* d_out, int out_size, void* d_ws, size_t ws_size,
                              hipStream_t stream) {
    const float* X  = (const float*)d_in[0];   // [32][2048][256]
    const float* Wi = (const float*)d_in[1];   // [256][1024]
    const float* Wh = (const float*)d_in[2];   // [256][1024]
    const float* bv = (const float*)d_in[3];   // [1024]
    const float* h0 = (const float*)d_in[4];   // [32][256]
    const float* c0 = (const float*)d_in[5];   // [32][256]
    float* out = (float*)d_out;

    char* ws = (char*)d_ws;
    uint4* Whp = (uint4*)(ws);                       // 512 KB
    uint4* Wip = (uint4*)(ws + (512 << 10));         // 512 KB
    unsigned short* XPh = (unsigned short*)(ws + (1 << 20));  // 128 MB

    pack_w<<<256, 256, 0, stream>>>(Wi, Wh, Whp, Wip);
    xproj_gemm<<<2048, 1024, 0, stream>>>(X, Wip, (ushort4*)XPh);
    lstm_rec<<<NB, 1024, 0, stream>>>(Whp, XPh, bv, h0, c0, out);
}

// Round 5
// 3927.024 us; speedup vs baseline: 2.2127x; 2.2127x over previous
//
#include <hip/hip_runtime.h>

#define TSEQ 2048
#define NB   32
#define HIDN 256
#define NG   1024   // 4*HID

typedef _Float16 half_t;
typedef _Float16 half2_t __attribute__((ext_vector_type(2)));

__device__ __forceinline__ float fdot2f16(unsigned int a, unsigned int b, float c) {
#if __has_builtin(__builtin_amdgcn_fdot2)
    return __builtin_amdgcn_fdot2(__builtin_bit_cast(half2_t, a),
                                  __builtin_bit_cast(half2_t, b), c, false);
#else
    half2_t x = __builtin_bit_cast(half2_t, a);
    half2_t y = __builtin_bit_cast(half2_t, b);
    return c + (float)x[0] * (float)y[0] + (float)x[1] * (float)y[1];
#endif
}

__device__ __forceinline__ unsigned int packh2(float lo, float hi) {
    half_t l = (half_t)lo, h = (half_t)hi;
    return (unsigned int)__builtin_bit_cast(unsigned short, l) |
           ((unsigned int)__builtin_bit_cast(unsigned short, h) << 16);
}

__device__ __forceinline__ float fast_exp2(float x) {
#if __has_builtin(__builtin_amdgcn_exp2f)
    return __builtin_amdgcn_exp2f(x);
#else
    return exp2f(x);
#endif
}
__device__ __forceinline__ float fast_rcp(float x) {
#if __has_builtin(__builtin_amdgcn_rcpf)
    return __builtin_amdgcn_rcpf(x);
#else
    return 1.0f / x;
#endif
}

__device__ __forceinline__ float tanh_fast(float x) {
    float e = fast_exp2(x * 2.885390082f);
    return 1.0f - 2.0f * fast_rcp(e + 1.0f);
}

// ---------------------------------------------------------------------------
// K1: pack weights.
//  Wh -> Whp, NEW layout for lstm_rec: Whp[chunk*1024 + t], chunk in [0,32).
//    gate g = chunk>>3, piece p = chunk&7; for t: kq = t&3, cg = t>>2,
//    col = g*256+cg, k0 = kq*64 + p*8.
//    uint4 component d: pack(Wh[k0+2d][col], Wh[k0+2d+1][col]).
//    lstm_rec keeps chunks 0..22 in VGPRs, stages chunks 23..31 in LDS.
//  Wi -> Wip, OLD layout for xproj_gemm (unchanged):
//    Wip[m4*1024+tt], col=(tt&3)*256+(tt>>2), pairs (m4*8+2d, m4*8+2d+1).
// ---------------------------------------------------------------------------
__global__ void pack_w(const float* __restrict__ Wi, const float* __restrict__ Wh,
                       uint4* __restrict__ Whp, uint4* __restrict__ Wip) {
    int idx = blockIdx.x * 256 + threadIdx.x;   // 0..65535
    if (idx < 32768) {
        int chunk = idx >> 10, t = idx & 1023;
        int g = chunk >> 3, p = chunk & 7;
        int kq = t & 3, cg = t >> 2;
        int col = g * 256 + cg;
        int k0 = kq * 64 + p * 8;
        Whp[idx] = make_uint4(
            packh2(Wh[(k0 + 0) * NG + col], Wh[(k0 + 1) * NG + col]),
            packh2(Wh[(k0 + 2) * NG + col], Wh[(k0 + 3) * NG + col]),
            packh2(Wh[(k0 + 4) * NG + col], Wh[(k0 + 5) * NG + col]),
            packh2(Wh[(k0 + 6) * NG + col], Wh[(k0 + 7) * NG + col]));
    } else {
        int li = idx & 32767;
        int m4 = li >> 10, tt = li & 1023;
        int col = (tt & 3) * 256 + (tt >> 2);
        int k0 = m4 * 8;
        Wip[li] = make_uint4(
            packh2(Wi[(k0 + 0) * NG + col], Wi[(k0 + 1) * NG + col]),
            packh2(Wi[(k0 + 2) * NG + col], Wi[(k0 + 3) * NG + col]),
            packh2(Wi[(k0 + 4) * NG + col], Wi[(k0 + 5) * NG + col]),
            packh2(Wi[(k0 + 6) * NG + col], Wi[(k0 + 7) * NG + col]));
    }
}

// ---------------------------------------------------------------------------
// K2: x_proj GEMM (unchanged): X [65536][256] fp32 @ Wi -> XP ushort4,
// gate-interleaved f16: half index row*1024 + j*4 + g.
// ---------------------------------------------------------------------------
__global__ __launch_bounds__(1024) void xproj_gemm(
    const float* __restrict__ X, const uint4* __restrict__ Wip,
    ushort4* __restrict__ XP)
{
    __shared__ uint4 atile[32][32];
    const int tid = threadIdx.x;
    const long row0 = (long)blockIdx.x * 32;

    {
        int r = tid >> 5, kc = tid & 31;
        const float4* src = (const float4*)(X + (row0 + r) * 256 + kc * 8);
        float4 f0 = src[0], f1 = src[1];
        atile[r][kc] = make_uint4(packh2(f0.x, f0.y), packh2(f0.z, f0.w),
                                  packh2(f1.x, f1.y), packh2(f1.z, f1.w));
    }
    __syncthreads();

    const int j = tid & 255, rq = tid >> 8;
    float acc[8][4];
#pragma unroll
    for (int r = 0; r < 8; ++r)
#pragma unroll
        for (int g = 0; g < 4; ++g) acc[r][g] = 0.f;

    unsigned off = (unsigned)(j * 4);
#pragma unroll 2
    for (int m4 = 0; m4 < 32; ++m4) {
        uint4 w0 = Wip[off + 0];
        uint4 w1 = Wip[off + 1];
        uint4 w2 = Wip[off + 2];
        uint4 w3 = Wip[off + 3];
#pragma unroll
        for (int rr = 0; rr < 8; ++rr) {
            uint4 av = atile[rq * 8 + rr][m4];
            acc[rr][0] = fdot2f16(w0.x, av.x, acc[rr][0]);
            acc[rr][0] = fdot2f16(w0.y, av.y, acc[rr][0]);
            acc[rr][0] = fdot2f16(w0.z, av.z, acc[rr][0]);
            acc[rr][0] = fdot2f16(w0.w, av.w, acc[rr][0]);
            acc[rr][1] = fdot2f16(w1.x, av.x, acc[rr][1]);
            acc[rr][1] = fdot2f16(w1.y, av.y, acc[rr][1]);
            acc[rr][1] = fdot2f16(w1.z, av.z, acc[rr][1]);
            acc[rr][1] = fdot2f16(w1.w, av.w, acc[rr][1]);
            acc[rr][2] = fdot2f16(w2.x, av.x, acc[rr][2]);
            acc[rr][2] = fdot2f16(w2.y, av.y, acc[rr][2]);
            acc[rr][2] = fdot2f16(w2.z, av.z, acc[rr][2]);
            acc[rr][2] = fdot2f16(w2.w, av.w, acc[rr][2]);
            acc[rr][3] = fdot2f16(w3.x, av.x, acc[rr][3]);
            acc[rr][3] = fdot2f16(w3.y, av.y, acc[rr][3]);
            acc[rr][3] = fdot2f16(w3.z, av.z, acc[rr][3]);
            acc[rr][3] = fdot2f16(w3.w, av.w, acc[rr][3]);
        }
        off += 1024;
    }

#pragma unroll
    for (int rr = 0; rr < 8; ++rr) {
        long row = row0 + rq * 8 + rr;
        XP[row * 256 + j] = make_ushort4(
            __builtin_bit_cast(unsigned short, (half_t)acc[rr][0]),
            __builtin_bit_cast(unsigned short, (half_t)acc[rr][1]),
            __builtin_bit_cast(unsigned short, (half_t)acc[rr][2]),
            __builtin_bit_cast(unsigned short, (half_t)acc[rr][3]));
    }
}

// ---------------------------------------------------------------------------
// K3: persistent recurrence, weights on-CU.
// 1 WG (1024 threads) per batch row. Thread tid = cg*4+kq owns the 4 gate
// columns of j=cg over k-quarter [kq*64, kq*64+64).
// Weights: chunks 0..22 in VGPRs (92 regs), chunks 23..31 in LDS (144 KB).
// Per step: 128 dot2 -> quad shfl_xor transpose-reduce (lane kq ends with
// gate kq of j=cg) -> in-quad gate combine -> lane kq==0 writes h (f16 LDS,
// double-buffered) + ys.  ONE barrier per step.
// ---------------------------------------------------------------------------
__global__ __launch_bounds__(1024) void lstm_rec(
    const uint4* __restrict__ Whp, const unsigned short* __restrict__ XPh,
    const float* __restrict__ bias, const float* __restrict__ h0,
    const float* __restrict__ c0, float* __restrict__ out)
{
    __shared__ __align__(16) uint4 wlds[9][1024];          // 144 KB
    __shared__ __align__(16) unsigned int hpair[2][128];   // 2 x 256 f16

    const int tid = threadIdx.x;
    const int b   = blockIdx.x;
    const int kq  = tid & 3;
    const int cg  = tid >> 2;

    // loop-invariant weights -> registers (static indices only)
    uint4 wr[23];
#pragma unroll
    for (int r = 0; r < 23; ++r) wr[r] = Whp[r * 1024 + tid];
    // remaining 9 chunks -> LDS
#pragma unroll
    for (int c = 0; c < 9; ++c) wlds[c][tid] = Whp[(23 + c) * 1024 + tid];

    const float bc = bias[kq * 256 + cg];
    float c_state  = c0[b * HIDN + cg];     // replicated across the quad
    if (tid < 256) {
        ((unsigned short*)hpair[0])[tid] =
            __builtin_bit_cast(unsigned short, (half_t)h0[b * HIDN + tid]);
    }
    const unsigned short* xp = XPh + (long)b * TSEQ * NG + tid;
    float* ys = out + 2 * NB * HIDN + (long)b * TSEQ * HIDN;
    __syncthreads();

    int buf = 0;
    for (int step = 0; step < TSEQ; ++step) {
        float xpf = (float)__builtin_bit_cast(half_t, xp[(long)step * NG]);

        const uint4* hv4 = (const uint4*)hpair[buf];
        float p0 = 0.f, p1 = 0.f, p2 = 0.f, p3 = 0.f;
#pragma unroll
        for (int p = 0; p < 8; ++p) {
            uint4 hv = hv4[kq * 8 + p];
            uint4 w0 = wr[p];
            uint4 w1 = wr[8 + p];
            uint4 w2 = (p < 7) ? wr[16 + p] : wlds[0][tid];
            uint4 w3 = wlds[1 + p][tid];
            p0 = fdot2f16(w0.x, hv.x, p0); p0 = fdot2f16(w0.y, hv.y, p0);
            p0 = fdot2f16(w0.z, hv.z, p0); p0 = fdot2f16(w0.w, hv.w, p0);
            p1 = fdot2f16(w1.x, hv.x, p1); p1 = fdot2f16(w1.y, hv.y, p1);
            p1 = fdot2f16(w1.z, hv.z, p1); p1 = fdot2f16(w1.w, hv.w, p1);
            p2 = fdot2f16(w2.x, hv.x, p2); p2 = fdot2f16(w2.y, hv.y, p2);
            p2 = fdot2f16(w2.z, hv.z, p2); p2 = fdot2f16(w2.w, hv.w, p2);
            p3 = fdot2f16(w3.x, hv.x, p3); p3 = fdot2f16(w3.y, hv.y, p3);
            p3 = fdot2f16(w3.z, hv.z, p3); p3 = fdot2f16(w3.w, hv.w, p3);
        }

        // quad transpose-reduce: lane kq ends with full z of gate kq, j=cg
        const int q0 = kq & 1, q1 = kq >> 1;
        float keepA = q0 ? p1 : p0;
        float sendA = q0 ? p0 : p1;
        float keepB = q0 ? p3 : p2;
        float sendB = q0 ? p2 : p3;
        keepA += __shfl_xor(sendA, 1);
        keepB += __shfl_xor(sendB, 1);
        float keep = q1 ? keepB : keepA;
        float send = q1 ? keepA : keepB;
        float z = keep + __shfl_xor(send, 2) + xpf + bc;

        // activation: shared exp2 path; gate 2 (kq==2) is tanh, others sigmoid
        float s  = (kq == 2) ? 2.885390082f : -1.442695041f;
        float e  = fast_exp2(z * s);
        float r  = fast_rcp(1.0f + e);
        float a  = (kq == 2) ? 1.0f - 2.0f * r : r;

        // in-quad all-gather of the 4 gate activations
        float b1 = __shfl_xor(a, 1);
        float b2 = __shfl_xor(a, 2);
        float b3 = __shfl_xor(b1, 2);
        float gi = (kq == 0) ? a : (kq == 1) ? b1 : (kq == 2) ? b2 : b3;
        float gf = (kq == 1) ? a : (kq == 0) ? b1 : (kq == 3) ? b2 : b3;
        float gg = (kq == 2) ? a : (kq == 3) ? b1 : (kq == 0) ? b2 : b3;
        float go = (kq == 3) ? a : (kq == 2) ? b1 : (kq == 1) ? b2 : b3;

        float cn = gf * c_state + gi * gg;
        float hn = go * tanh_fast(cn);
        c_state = cn;

        if (kq == 0) {
            ((unsigned short*)hpair[buf ^ 1])[cg] =
                __builtin_bit_cast(unsigned short, (half_t)hn);
            ys[(long)step * HIDN + cg] = hn;
            if (step == TSEQ - 1) {
                out[b * HIDN + cg] = hn;                  // hT
                out[NB * HIDN + b * HIDN + cg] = cn;      // cT
            }
        }
        __syncthreads();
        buf ^= 1;
    }
}

// ---------------------------------------------------------------------------
extern "C" void kernel_launch(void* const* d_in, const int* in_sizes, int n_in,
                              void* d_out, int out_size, void* d_ws, size_t ws_size,
                              hipStream_t stream) {
    const float* X  = (const float*)d_in[0];   // [32][2048][256]
    const float* Wi = (const float*)d_in[1];   // [256][1024]
    const float* Wh = (const float*)d_in[2];   // [256][1024]
    const float* bv = (const float*)d_in[3];   // [1024]
    const float* h0 = (const float*)d_in[4];   // [32][256]
    const float* c0 = (const float*)d_in[5];   // [32][256]
    float* out = (float*)d_out;

    char* ws = (char*)d_ws;
    uint4* Whp = (uint4*)(ws);                       // 512 KB
    uint4* Wip = (uint4*)(ws + (512 << 10));         // 512 KB
    unsigned short* XPh = (unsigned short*)(ws + (1 << 20));  // 128 MB

    pack_w<<<256, 256, 0, stream>>>(Wi, Wh, Whp, Wip);
    xproj_gemm<<<2048, 1024, 0, stream>>>(X, Wip, (ushort4*)XPh);
    lstm_rec<<<NB, 1024, 0, stream>>>(Whp, XPh, bv, h0, c0, out);
}